// Round 9
// baseline (3243.411 us; speedup 1.0000x reference)
//
#include <hip/hip_runtime.h>

typedef unsigned short u16;
typedef unsigned int   u32;
typedef unsigned long long u64;
typedef short v8s __attribute__((ext_vector_type(8)));
typedef float v16f __attribute__((ext_vector_type(16)));
typedef float v2f  __attribute__((ext_vector_type(2)));
typedef float v4f  __attribute__((ext_vector_type(4)));

#define B_ 512
#define I_ 128
#define H_ 512
#define KK 640
#define NSTEP 512
#define AST 648   // A-tile row stride, u16 elems (1296 B = 324 dw, 324%32=4 -> even bank spread)

__device__ inline u16 f2b(float x){
  union{float f; unsigned u;} v; v.f = x;
  unsigned r = v.u + 0x7fffu + ((v.u >> 16) & 1u);
  return (u16)(r >> 16);
}

// overflow-safe fast tanh: x->+inf => 1, x->-inf => -1 (exp underflow)
__device__ inline float tanh_fast(float x){
  float e = __expf(2.f * x);
  return 1.f - 2.f / (e + 1.f);
}

// All cross-wg traffic: relaxed agent-scope atomics -> L3 = coherence point.
__device__ inline u64 ld64(const u16* p){
  return __hip_atomic_load((const u64*)p, __ATOMIC_RELAXED, __HIP_MEMORY_SCOPE_AGENT);
}
__device__ inline void st32(u16* p, u32 v){
  __hip_atomic_store((u32*)p, v, __ATOMIC_RELAXED, __HIP_MEMORY_SCOPE_AGENT);
}
__device__ inline u32 fpoll(const u32* p){
  return __hip_atomic_load(p, __ATOMIC_RELAXED, __HIP_MEMORY_SCOPE_AGENT);
}
__device__ inline void fst(u32* p, u32 v){
  __hip_atomic_store(p, v, __ATOMIC_RELAXED, __HIP_MEMORY_SCOPE_AGENT);
}
// LDS pair-flag ops (workgroup scope -> plain ds, re-read every poll)
__device__ inline u32 lpoll(const u32* p){
  return __hip_atomic_load(p, __ATOMIC_RELAXED, __HIP_MEMORY_SCOPE_WORKGROUP);
}
__device__ inline void lst(u32* p, u32 v){
  __hip_atomic_store(p, v, __ATOMIC_RELAXED, __HIP_MEMORY_SCOPE_WORKGROUP);
}

// Prep: Wcat[gcol][k] = [W_hh (k<512) | W_ih (k>=512)] bf16, fcW bf16, fused
// bias, h0 bf16, out0 = x[511] bf16, zeroed flags. Re-runs every call.
__global__ void init_kernel(const float* __restrict__ x, const float* __restrict__ h0,
    const float* __restrict__ Wih, const float* __restrict__ Whh,
    const float* __restrict__ bih, const float* __restrict__ bhh, const float* __restrict__ fcW,
    u16* __restrict__ Wcat, u16* __restrict__ fcWb, float* __restrict__ bsum,
    u16* __restrict__ hb0, u16* __restrict__ outb, u32* __restrict__ flags)
{
  int idx = blockIdx.x * 256 + threadIdx.x;
  if (idx < 1310720) {                       // Wcat: 2048 x 640, [Whh | Wih]
    int g = idx / 640, k = idx - g * 640;
    float v = (k < 512) ? Whh[g * 512 + k] : Wih[g * 128 + (k - 512)];
    Wcat[idx] = f2b(v);
  } else if (idx < 1376256) {                // fcW bf16: 128 x 512
    int i = idx - 1310720; fcWb[i] = f2b(fcW[i]);
  } else if (idx < 1378304) {                // fused bias: 2048
    int i = idx - 1376256; bsum[i] = bih[i] + bhh[i];
  } else if (idx < 1640448) {                // h init: 512 x 512
    int i = idx - 1378304; hb0[i] = f2b(h0[i]);
  } else if (idx < 1705984) {                // inp init = x[511]: 512 x 128
    int i = idx - 1640448; outb[i] = f2b(x[33488896 + i]);
  } else if (idx < 1706240) {                // flags[16 groups][16 wgs]
    flags[idx - 1705984] = 0u;
  }
}

// Persistent decoder, grid = 256 x 512 threads (1 wg/CU, 8 waves = 2/SIMD).
// 16 groups x 16 wgs; group mb owns rows mb*32..+32, wg nb owns h-cols
// nb*32..+32.
// R9 = R3 (2770us) + k-split wave pairs: pair p = (wave p, wave p+4) owns
// gate-tile Gp (gate p, cols nb*32..+32, k=640) AND fc-tile Fp (out-cols
// p*32..+32, k=512). Low wave: kc[0,16) of BOTH per A-read (2 MFMA per
// ds_read_b128); high wave: kc[16,32) of both + phase-2 (kc 32..40).
// Per-CU A-reads 288 -> 160 b128. Partial sums cross the pair via LDS xbuf
// (conflict-free float4 chunks) with PAIR-LOCAL LDS token flags (write ->
// lgkmcnt(0) -> token; partner spins) -- no extra wg barrier; WAR across
// steps is ordered by bars A/B. fc-act on low waves, gate-act on high.
// Cell, gather, poll, deferred dout: byte-identical to R3. 4 barriers.
__global__ __launch_bounds__(512, 2) void decoder_persist(
    const u16* __restrict__ Wcat, const float* __restrict__ bsum,
    const u16* __restrict__ fcWb, const float* __restrict__ fcb,
    const float* __restrict__ c0,
    u16* __restrict__ hb0, u16* __restrict__ hb1, const u16* __restrict__ outb,
    float* __restrict__ dout, u32* __restrict__ flags)
{
  __shared__ __align__(16) u16  Alds[32 * AST];   // 32 x (512 h | 128 out | 8 pad)
  __shared__ __align__(16) float gbuf[4096];      // 4 gates x 32 x 32 exchange
  __shared__ __align__(16) v4f  xbuf[2048];       // acc exchange: G [0,1024), F [1024,2048)
  __shared__ u32 xfl[8];                          // pair tokens: [0..4)=G ready, [4..8)=F

  const int tid  = threadIdx.x;
  const int wid  = tid >> 6, lane = tid & 63;
  const int l31  = lane & 31, q2 = lane >> 5;     // MFMA: col = lane&31, k-half = lane>>5
  const int mb   = blockIdx.x & 15;               // group (co-XCD under round-robin; perf-only)
  const int nb   = blockIdx.x >> 4;               // col-slice 0..15
  const int R    = mb * 32;
  u32* gf = flags + mb * 16;

  const bool islow = (wid < 4);
  const int  p     = islow ? wid : (wid - 4);     // pair index = gate = fc-block
  const int  kb    = islow ? 0 : 16;              // phase-1 kc base

  if (tid < 8) xfl[tid] = 0;                      // ordered vs first use by bar A(t=0)

  // ---- resident weights: low 32 v8s (128 regs), high 40 v8s (160 regs) ----
  v8s wG[24], wF[16];
  {
    const u16* wr = Wcat + (u64)(p * 512 + nb * 32 + l31) * KK + q2 * 8;
    #pragma unroll
    for (int kc = 0; kc < 16; ++kc) wG[kc] = *reinterpret_cast<const v8s*>(wr + (kb + kc) * 16);
    if (!islow) {
      #pragma unroll
      for (int kc = 16; kc < 24; ++kc)            // phase-2 frags: k-steps 32..40
        wG[kc] = *reinterpret_cast<const v8s*>(wr + (kb + kc) * 16);
    }
    const u16* fr = fcWb + (u64)(p * 32 + l31) * H_ + q2 * 8;
    #pragma unroll
    for (int kc = 0; kc < 16; ++kc) wF[kc] = *reinterpret_cast<const v8s*>(fr + (kb + kc) * 16);
  }
  // low: fc bias (fc-act there); high: gate bias (gate-act there)
  const float bias0 = islow ? fcb[p * 32 + l31] : bsum[p * 512 + nb * 32 + l31];

  // dout ownership (low waves): out-col (p*32+l31), wg nb owns cols [8nb,8nb+8)
  const bool dopred = islow && (((p * 32 + l31) >> 3) == nb);

  float oreg[16];
  float* dpend = nullptr;

  // c state: 2 elems/thread: (crow, ccol..ccol+1) of the wg's 32x32 h-tile
  const int crow = tid >> 4, ccol = (tid * 2) & 31;
  float cv0 = c0[(R + crow) * H_ + nb * 32 + ccol];
  float cv1 = c0[(R + crow) * H_ + nb * 32 + ccol + 1];

  for (int t = 0; t <= NSTEP; ++t) {
    const u16* hsrc = (t & 1) ? hb1 : hb0;

    // ---- flush deferred dout (issued before the poll: progresses during
    //      the spin, acked long before any drain point) ----
    if (dopred && dpend) {
      #pragma unroll
      for (int r = 0; r < 16; ++r) {
        int row = (r & 3) + 8 * (r >> 2) + 4 * q2;
        __builtin_nontemporal_store(oreg[r], dpend + (R + row) * I_ + p * 32 + l31);
      }
      dpend = nullptr;
    }

    // ---- per-wave poll: wave w needs slices {2w, 2w+1} for its gather ----
    if (t > 0) {
      const u32 tt = (u32)t;
      for (;;) {
        u32 f = fpoll(gf + 2 * wid + (lane & 1));
        if (__all((int)(f >= tt))) break;
      }
      __asm__ volatile("" ::: "memory");
    }

    // ---- gather: wave w stages h-cols [64w, 64w+64): 8 u64/lane ----
    {
      u64 tmp[8];
      #pragma unroll
      for (int k = 0; k < 8; ++k) {
        int v = k * 64 + lane;
        int row = v >> 4, c16 = v & 15;
        tmp[k] = ld64(hsrc + (R + row) * H_ + wid * 64 + c16 * 4);
      }
      #pragma unroll
      for (int k = 0; k < 8; ++k) {
        int v = k * 64 + lane;
        int row = v >> 4, c16 = v & 15;
        *reinterpret_cast<u64*>(&Alds[row * AST + wid * 64 + c16 * 4]) = tmp[k];
      }
    }
    if (t == 0) {                       // out(-1) = x[511] (preconverted)
      u64 tp2[2];
      #pragma unroll
      for (int u = 0; u < 2; ++u) {
        int v = u * 512 + tid;
        int row = v >> 5, cc = v & 31;
        tp2[u] = ld64(outb + (R + row) * I_ + cc * 4);
      }
      #pragma unroll
      for (int u = 0; u < 2; ++u) {
        int v = u * 512 + tid;
        int row = v >> 5, cc = v & 31;
        *reinterpret_cast<u64*>(&Alds[row * AST + 512 + cc * 4]) = tp2[u];
      }
    }
    __syncthreads();                    // bar A: A-tile h-region ready

    // ---- phase 1 (half-K): one A-read feeds G AND F MFMA ----
    v16f accG = {0.f,0.f,0.f,0.f,0.f,0.f,0.f,0.f,0.f,0.f,0.f,0.f,0.f,0.f,0.f,0.f};
    v16f accF = {0.f,0.f,0.f,0.f,0.f,0.f,0.f,0.f,0.f,0.f,0.f,0.f,0.f,0.f,0.f,0.f};
    const u16* ab = &Alds[l31 * AST + q2 * 8];
    __builtin_amdgcn_s_setprio(1);
    #pragma unroll
    for (int kc = 0; kc < 16; ++kc) {
      v8s a = *reinterpret_cast<const v8s*>(ab + (kb + kc) * 16);
      accG = __builtin_amdgcn_mfma_f32_32x32x16_bf16(a, wG[kc], accG, 0, 0, 0);
      accF = __builtin_amdgcn_mfma_f32_32x32x16_bf16(a, wF[kc], accF, 0, 0, 0);
    }
    __builtin_amdgcn_s_setprio(0);

    // ---- pair exchange via LDS tokens (no wg barrier) ----
    const u32 tok = (u32)(t + 1);
    if (islow) {
      // send accG_lo -> high
      #pragma unroll
      for (int j = 0; j < 4; ++j)
        xbuf[(p * 4 + j) * 64 + lane] = (v4f){accG[4*j], accG[4*j+1], accG[4*j+2], accG[4*j+3]};
      asm volatile("s_waitcnt lgkmcnt(0)" ::: "memory");
      lst(&xfl[p], tok);
      while (lpoll(&xfl[4 + p]) < tok) {}
      __asm__ volatile("" ::: "memory");
      // receive accF_hi
      #pragma unroll
      for (int j = 0; j < 4; ++j) {
        v4f q = xbuf[1024 + (p * 4 + j) * 64 + lane];
        accF[4*j] += q[0]; accF[4*j+1] += q[1]; accF[4*j+2] += q[2]; accF[4*j+3] += q[3];
      }
      // ---- fc act: out(t-1) = 2*sigmoid(.)-1 -> LDS feedback + oreg ----
      if (t > 0) {
        #pragma unroll
        for (int r = 0; r < 16; ++r) {
          int row = (r & 3) + 8 * (r >> 2) + 4 * q2;   // 32x32 C-layout
          float o = 2.f / (1.f + __expf(-(accF[r] + bias0))) - 1.f;
          oreg[r] = o;
          Alds[row * AST + 512 + p * 32 + l31] = f2b(o);
        }
        dpend = dout + (u64)(NSTEP - t) * (B_ * I_);
      }
    } else {
      // send accF_hi -> low
      #pragma unroll
      for (int j = 0; j < 4; ++j)
        xbuf[1024 + (p * 4 + j) * 64 + lane] = (v4f){accF[4*j], accF[4*j+1], accF[4*j+2], accF[4*j+3]};
      asm volatile("s_waitcnt lgkmcnt(0)" ::: "memory");
      lst(&xfl[4 + p], tok);
      while (lpoll(&xfl[p]) < tok) {}
      __asm__ volatile("" ::: "memory");
      // receive accG_lo
      #pragma unroll
      for (int j = 0; j < 4; ++j) {
        v4f q = xbuf[(p * 4 + j) * 64 + lane];
        accG[4*j] += q[0]; accG[4*j+1] += q[1]; accG[4*j+2] += q[2]; accG[4*j+3] += q[3];
      }
    }
    __syncthreads();                    // bar B: out region ready (also WAR-fences xbuf)

    if (t < NSTEP) {
      if (!islow) {
        // ---- phase 2: k-steps 32..40 (out part) -> accG complete ----
        __builtin_amdgcn_s_setprio(1);
        #pragma unroll
        for (int kc = 16; kc < 24; ++kc) {
          v8s a = *reinterpret_cast<const v8s*>(ab + (kb + kc) * 16);
          accG = __builtin_amdgcn_mfma_f32_32x32x16_bf16(a, wG[kc], accG, 0, 0, 0);
        }
        __builtin_amdgcn_s_setprio(0);
        // ---- gate activation -> gbuf (gate p) ----
        #pragma unroll
        for (int r = 0; r < 16; ++r) {
          int row = (r & 3) + 8 * (r >> 2) + 4 * q2;
          float z = accG[r] + bias0;
          float a2 = (p == 2) ? tanh_fast(z) : 1.f / (1.f + __expf(-z));
          gbuf[p * 1024 + row * 32 + l31] = a2;
        }
      }
      __syncthreads();                  // bar C: gbuf ready

      // ---- cell: c in regs, h(t+1) packed u32 -> L3 ----
      u16* hdst = (t & 1) ? hb0 : hb1;
      v2f ig = *reinterpret_cast<const v2f*>(&gbuf[       crow * 32 + ccol]);
      v2f fg = *reinterpret_cast<const v2f*>(&gbuf[1024 + crow * 32 + ccol]);
      v2f gg = *reinterpret_cast<const v2f*>(&gbuf[2048 + crow * 32 + ccol]);
      v2f og = *reinterpret_cast<const v2f*>(&gbuf[3072 + crow * 32 + ccol]);
      float cn0 = fg[0] * cv0 + ig[0] * gg[0];
      float cn1 = fg[1] * cv1 + ig[1] * gg[1];
      cv0 = cn0; cv1 = cn1;
      u32 packed = (u32)f2b(og[0] * tanh_fast(cn0)) | ((u32)f2b(og[1] * tanh_fast(cn1)) << 16);
      st32(hdst + (R + crow) * H_ + nb * 32 + ccol, packed);
      __syncthreads();                  // bar D: vmcnt(0) drain, h acked at L3
      __asm__ volatile("" ::: "memory");
      if (tid == 0) fst(gf + nb, (u32)(t + 1));
    }
  }

  // ---- final dout flush (out(511), computed at t = NSTEP) ----
  if (dopred && dpend) {
    #pragma unroll
    for (int r = 0; r < 16; ++r) {
      int row = (r & 3) + 8 * (r >> 2) + 4 * q2;
      __builtin_nontemporal_store(oreg[r], dpend + (R + row) * I_ + p * 32 + l31);
    }
  }
}

extern "C" void kernel_launch(void* const* d_in, const int* in_sizes, int n_in,
                              void* d_out, int out_size, void* d_ws, size_t ws_size,
                              hipStream_t stream)
{
  const float* x   = (const float*)d_in[0];
  // d_in[1] = enc_hiddens: unused by the reference
  const float* h0  = (const float*)d_in[2];
  const float* c0  = (const float*)d_in[3];
  const float* Wih = (const float*)d_in[4];
  const float* Whh = (const float*)d_in[5];
  const float* bih = (const float*)d_in[6];
  const float* bhh = (const float*)d_in[7];
  const float* fcW = (const float*)d_in[8];
  const float* fcb = (const float*)d_in[9];

  char* p = (char*)d_ws;
  u16*   Wcat  = (u16*)p;   p += 2048LL * 640 * 2;
  u16*   fcWb  = (u16*)p;   p += 128 * 512 * 2;
  float* bsum  = (float*)p; p += 2048 * 4;
  u16*   hb0   = (u16*)p;   p += 512 * 512 * 2;
  u16*   hb1   = (u16*)p;   p += 512 * 512 * 2;
  u16*   outb  = (u16*)p;   p += 512 * 128 * 2;
  u32*   flags = (u32*)p;   p += 256 * 4;
  float* dout  = (float*)d_out;

  init_kernel<<<6666, 256, 0, stream>>>(x, h0, Wih, Whh, bih, bhh, fcW,
                                        Wcat, fcWb, bsum, hb0, outb, flags);
  decoder_persist<<<256, 512, 0, stream>>>(Wcat, bsum, fcWb, fcb, c0,
                                           hb0, hb1, outb, dout, flags);
}

// Round 11
// 2769.528 us; speedup vs baseline: 1.1711x; 1.1711x over previous
//
#include <hip/hip_runtime.h>

typedef unsigned short u16;
typedef unsigned int   u32;
typedef unsigned long long u64;
typedef short v8s __attribute__((ext_vector_type(8)));
typedef float v16f __attribute__((ext_vector_type(16)));
typedef float v2f  __attribute__((ext_vector_type(2)));

#define B_ 512
#define I_ 128
#define H_ 512
#define KK 640
#define NSTEP 512
#define AST 648   // A-tile row stride, u16 elems (1296 B = 324 dw, 324%32=4 -> even bank spread)

__device__ inline u16 f2b(float x){
  union{float f; unsigned u;} v; v.f = x;
  unsigned r = v.u + 0x7fffu + ((v.u >> 16) & 1u);
  return (u16)(r >> 16);
}

// overflow-safe fast tanh: x->+inf => 1, x->-inf => -1 (exp underflow)
__device__ inline float tanh_fast(float x){
  float e = __expf(2.f * x);
  return 1.f - 2.f / (e + 1.f);
}

// All cross-wg traffic: relaxed agent-scope atomics -> L3 = coherence point.
__device__ inline u64 ld64(const u16* p){
  return __hip_atomic_load((const u64*)p, __ATOMIC_RELAXED, __HIP_MEMORY_SCOPE_AGENT);
}
__device__ inline void st32(u16* p, u32 v){
  __hip_atomic_store((u32*)p, v, __ATOMIC_RELAXED, __HIP_MEMORY_SCOPE_AGENT);
}
__device__ inline u32 fpoll(const u32* p){
  return __hip_atomic_load(p, __ATOMIC_RELAXED, __HIP_MEMORY_SCOPE_AGENT);
}
__device__ inline void fst(u32* p, u32 v){
  __hip_atomic_store(p, v, __ATOMIC_RELAXED, __HIP_MEMORY_SCOPE_AGENT);
}

// Prep: Wcat[gcol][k] = [W_hh (k<512) | W_ih (k>=512)] bf16, fcW bf16, fused
// bias, h0 bf16, out0 = x[511] bf16, zeroed flags. Re-runs every call.
__global__ void init_kernel(const float* __restrict__ x, const float* __restrict__ h0,
    const float* __restrict__ Wih, const float* __restrict__ Whh,
    const float* __restrict__ bih, const float* __restrict__ bhh, const float* __restrict__ fcW,
    u16* __restrict__ Wcat, u16* __restrict__ fcWb, float* __restrict__ bsum,
    u16* __restrict__ hb0, u16* __restrict__ outb, u32* __restrict__ flags)
{
  int idx = blockIdx.x * 256 + threadIdx.x;
  if (idx < 1310720) {                       // Wcat: 2048 x 640, [Whh | Wih]
    int g = idx / 640, k = idx - g * 640;
    float v = (k < 512) ? Whh[g * 512 + k] : Wih[g * 128 + (k - 512)];
    Wcat[idx] = f2b(v);
  } else if (idx < 1376256) {                // fcW bf16: 128 x 512
    int i = idx - 1310720; fcWb[i] = f2b(fcW[i]);
  } else if (idx < 1378304) {                // fused bias: 2048
    int i = idx - 1376256; bsum[i] = bih[i] + bhh[i];
  } else if (idx < 1640448) {                // h init: 512 x 512
    int i = idx - 1378304; hb0[i] = f2b(h0[i]);
  } else if (idx < 1705984) {                // inp init = x[511]: 512 x 128
    int i = idx - 1640448; outb[i] = f2b(x[33488896 + i]);
  } else if (idx < 1706240) {                // flags[16 groups][16 wgs]
    flags[idx - 1705984] = 0u;
  }
}

// Persistent decoder, grid = 256 x 512 threads (1 wg/CU, 8 waves = 2/SIMD).
// 16 groups x 16 wgs; group mb owns rows mb*32..+32, wg nb owns h-cols
// nb*32..+32. Waves 0-3: gate wid (i,f,g,o), 32x32 tile k=640. Waves 4-7:
// redundant local fc, out-cols (wid-4)*32..+32, k=512. Phase-1 (k<512) is
// the same loop for both roles.
// (a) per-wave poll+gather: wave w polls only flags {2w,2w+1} covering its
// 64-col gather slice, then gathers immediately -- stragglers block one wave,
// not the wg. (b) dout stores deferred to the next iteration's poll/gather
// window (register-held) so their HBM ack never sits inside a barrier drain.
// (c) s_setprio(1) around the MFMA loops.
__global__ __launch_bounds__(512, 2) void decoder_persist(
    const u16* __restrict__ Wcat, const float* __restrict__ bsum,
    const u16* __restrict__ fcWb, const float* __restrict__ fcb,
    const float* __restrict__ c0,
    u16* __restrict__ hb0, u16* __restrict__ hb1, const u16* __restrict__ outb,
    float* __restrict__ dout, u32* __restrict__ flags)
{
  __shared__ __align__(16) u16  Alds[32 * AST];   // 32 x (512 h | 128 out | 8 pad)
  __shared__ __align__(16) float gbuf[4096];      // 4 gates x 32 x 32 exchange

  const int tid  = threadIdx.x;
  const int wid  = tid >> 6, lane = tid & 63;
  const int l31  = lane & 31, q2 = lane >> 5;     // MFMA: col = lane&31, k-half = lane>>5
  const int mb   = blockIdx.x & 15;               // group (co-XCD under round-robin; perf-only)
  const int nb   = blockIdx.x >> 4;               // col-slice 0..15
  const int R    = mb * 32;
  u32* gf = flags + mb * 16;

  const bool isfc = (wid >= 4);
  const int  wc   = (wid - 4) * 32;               // fc out-col base (fc waves only)

  // ---- resident weights: 40 x v8s = 160 regs/lane (AGPR-backed) ----
  v8s wfrag[40];
  if (!isfc) {
    const u16* wr = Wcat + (u64)(wid * 512 + nb * 32 + l31) * KK + q2 * 8;
    #pragma unroll
    for (int kc = 0; kc < 40; ++kc) wfrag[kc] = *reinterpret_cast<const v8s*>(wr + kc * 16);
  } else {
    const u16* fr = fcWb + (u64)(wc + l31) * H_ + q2 * 8;
    #pragma unroll
    for (int kc = 0; kc < 32; ++kc) wfrag[kc] = *reinterpret_cast<const v8s*>(fr + kc * 16);
    #pragma unroll
    for (int kc = 32; kc < 40; ++kc) wfrag[kc] = (v8s){0,0,0,0,0,0,0,0};
  }
  const float bias0 = isfc ? fcb[wc + l31] : bsum[wid * 512 + nb * 32 + l31];

  // dout ownership: out-col (wc+l31) written by wg nb == col>>3 (8 cols/wg)
  const bool dopred = isfc && (((wc + l31) >> 3) == nb);

  // deferred dout state: 16 outputs of fc-act held in regs, flushed next iter
  float oreg[16];
  float* dpend = nullptr;

  // c state: 2 elems/thread: (crow, ccol..ccol+1) of the wg's 32x32 h-tile
  const int crow = tid >> 4, ccol = (tid * 2) & 31;
  float cv0 = c0[(R + crow) * H_ + nb * 32 + ccol];
  float cv1 = c0[(R + crow) * H_ + nb * 32 + ccol + 1];

  for (int t = 0; t <= NSTEP; ++t) {
    const u16* hsrc = (t & 1) ? hb1 : hb0;

    // ---- flush deferred dout (fire-and-forget; drains at post-gather bar,
    //      fully overlapped with the flag spin + gather latency) ----
    if (dopred && dpend) {
      #pragma unroll
      for (int r = 0; r < 16; ++r) {
        int row = (r & 3) + 8 * (r >> 2) + 4 * q2;
        __builtin_nontemporal_store(oreg[r], dpend + (R + row) * I_ + wc + l31);
      }
      dpend = nullptr;
    }

    // ---- per-wave poll: wave w needs slices {2w, 2w+1} for its gather ----
    if (t > 0) {
      const u32 tt = (u32)t;
      for (;;) {
        u32 f = fpoll(gf + 2 * wid + (lane & 1));
        if (__all((int)(f >= tt))) break;
      }
      __asm__ volatile("" ::: "memory");
    }

    // ---- gather: wave w stages h-cols [64w, 64w+64): 8 u64/lane ----
    {
      u64 tmp[8];
      #pragma unroll
      for (int k = 0; k < 8; ++k) {
        int v = k * 64 + lane;
        int row = v >> 4, c16 = v & 15;
        tmp[k] = ld64(hsrc + (R + row) * H_ + wid * 64 + c16 * 4);
      }
      #pragma unroll
      for (int k = 0; k < 8; ++k) {
        int v = k * 64 + lane;
        int row = v >> 4, c16 = v & 15;
        *reinterpret_cast<u64*>(&Alds[row * AST + wid * 64 + c16 * 4]) = tmp[k];
      }
    }
    if (t == 0) {                       // out(-1) = x[511] (preconverted)
      u64 tmp[2];
      #pragma unroll
      for (int u = 0; u < 2; ++u) {
        int v = u * 512 + tid;
        int row = v >> 5, cc = v & 31;
        tmp[u] = ld64(outb + (R + row) * I_ + cc * 4);
      }
      #pragma unroll
      for (int u = 0; u < 2; ++u) {
        int v = u * 512 + tid;
        int row = v >> 5, cc = v & 31;
        *reinterpret_cast<u64*>(&Alds[row * AST + 512 + cc * 4]) = tmp[u];
      }
    }
    __syncthreads();                    // bar A: A-tile h-region ready

    // ---- phase 1: k = 0..512 (h part), identical for gate and fc waves ----
    v16f acc = {0.f,0.f,0.f,0.f,0.f,0.f,0.f,0.f,0.f,0.f,0.f,0.f,0.f,0.f,0.f,0.f};
    const u16* ab = &Alds[l31 * AST + q2 * 8];
    __builtin_amdgcn_s_setprio(1);
    #pragma unroll
    for (int kc = 0; kc < 32; ++kc) {
      v8s a = *reinterpret_cast<const v8s*>(ab + kc * 16);
      acc = __builtin_amdgcn_mfma_f32_32x32x16_bf16(a, wfrag[kc], acc, 0, 0, 0);
    }
    __builtin_amdgcn_s_setprio(0);

    // ---- fc act: out(t-1) = 2*sigmoid(.)-1 -> LDS feedback + oreg ----
    if (isfc && t > 0) {
      #pragma unroll
      for (int r = 0; r < 16; ++r) {
        int row = (r & 3) + 8 * (r >> 2) + 4 * q2;   // 32x32 C-layout
        float o = 2.f / (1.f + __expf(-(acc[r] + bias0))) - 1.f;
        oreg[r] = o;
        Alds[row * AST + 512 + wc + l31] = f2b(o);
      }
      dpend = dout + (u64)(NSTEP - t) * (B_ * I_);
    }
    __syncthreads();                    // bar B: out region ready

    if (t < NSTEP) {
      if (!isfc) {
        // ---- phase 2: k = 512..640 (out part) ----
        __builtin_amdgcn_s_setprio(1);
        #pragma unroll
        for (int kc = 32; kc < 40; ++kc) {
          v8s a = *reinterpret_cast<const v8s*>(ab + kc * 16);
          acc = __builtin_amdgcn_mfma_f32_32x32x16_bf16(a, wfrag[kc], acc, 0, 0, 0);
        }
        __builtin_amdgcn_s_setprio(0);
        // ---- gate activation -> gbuf ----
        #pragma unroll
        for (int r = 0; r < 16; ++r) {
          int row = (r & 3) + 8 * (r >> 2) + 4 * q2;
          float z = acc[r] + bias0;
          float a2 = (wid == 2) ? tanh_fast(z) : 1.f / (1.f + __expf(-z));
          gbuf[wid * 1024 + row * 32 + l31] = a2;
        }
      }
      __syncthreads();                  // bar C: gbuf ready

      // ---- cell: c in regs, h(t+1) packed u32 -> L3 ----
      u16* hdst = (t & 1) ? hb0 : hb1;
      v2f ig = *reinterpret_cast<const v2f*>(&gbuf[       crow * 32 + ccol]);
      v2f fg = *reinterpret_cast<const v2f*>(&gbuf[1024 + crow * 32 + ccol]);
      v2f gg = *reinterpret_cast<const v2f*>(&gbuf[2048 + crow * 32 + ccol]);
      v2f og = *reinterpret_cast<const v2f*>(&gbuf[3072 + crow * 32 + ccol]);
      float cn0 = fg[0] * cv0 + ig[0] * gg[0];
      float cn1 = fg[1] * cv1 + ig[1] * gg[1];
      cv0 = cn0; cv1 = cn1;
      u32 packed = (u32)f2b(og[0] * tanh_fast(cn0)) | ((u32)f2b(og[1] * tanh_fast(cn1)) << 16);
      st32(hdst + (R + crow) * H_ + nb * 32 + ccol, packed);
      __syncthreads();                  // bar D: vmcnt(0) drain, h acked at L3
      __asm__ volatile("" ::: "memory");
      if (tid == 0) fst(gf + nb, (u32)(t + 1));
    }
  }

  // ---- final dout flush (out(511), computed at t = NSTEP) ----
  if (dopred && dpend) {
    #pragma unroll
    for (int r = 0; r < 16; ++r) {
      int row = (r & 3) + 8 * (r >> 2) + 4 * q2;
      __builtin_nontemporal_store(oreg[r], dpend + (R + row) * I_ + wc + l31);
    }
  }
}

extern "C" void kernel_launch(void* const* d_in, const int* in_sizes, int n_in,
                              void* d_out, int out_size, void* d_ws, size_t ws_size,
                              hipStream_t stream)
{
  const float* x   = (const float*)d_in[0];
  // d_in[1] = enc_hiddens: unused by the reference
  const float* h0  = (const float*)d_in[2];
  const float* c0  = (const float*)d_in[3];
  const float* Wih = (const float*)d_in[4];
  const float* Whh = (const float*)d_in[5];
  const float* bih = (const float*)d_in[6];
  const float* bhh = (const float*)d_in[7];
  const float* fcW = (const float*)d_in[8];
  const float* fcb = (const float*)d_in[9];

  char* p = (char*)d_ws;
  u16*   Wcat  = (u16*)p;   p += 2048LL * 640 * 2;
  u16*   fcWb  = (u16*)p;   p += 128 * 512 * 2;
  float* bsum  = (float*)p; p += 2048 * 4;
  u16*   hb0   = (u16*)p;   p += 512 * 512 * 2;
  u16*   hb1   = (u16*)p;   p += 512 * 512 * 2;
  u16*   outb  = (u16*)p;   p += 512 * 128 * 2;
  u32*   flags = (u32*)p;   p += 256 * 4;
  float* dout  = (float*)d_out;

  init_kernel<<<6666, 256, 0, stream>>>(x, h0, Wih, Whh, bih, bhh, fcW,
                                        Wcat, fcWb, bsum, hb0, outb, flags);
  decoder_persist<<<256, 512, 0, stream>>>(Wcat, bsum, fcWb, fcb, c0,
                                           hb0, hb1, outb, dout, flags);
}